// Round 4
// baseline (118.859 us; speedup 1.0000x reference)
//
#include <hip/hip_runtime.h>
#include <cstddef>

constexpr float GAMMA = 0.99f;
constexpr float GLAM  = 0.99f * 0.95f;   // gamma * gae_lambda
constexpr float ENT_C = 0.01f;

constexpr int T = 65536;
constexpr int O = 8;
constexpr int S = 1048576;
constexpr int BLK = 256;

constexpr int BPO        = 512;              // opponent blocks per o
constexpr int OPP_BLOCKS = O * BPO;          // 4096
constexpr int ROWS_PER_B = S / BPO;          // 2048 rows per block
constexpr int CHUNK      = T / BLK;          // 256 elements per thread in agent scan

typedef float f4 __attribute__((ext_vector_type(4)));
typedef int   i4 __attribute__((ext_vector_type(4)));

template <typename Tp>
__device__ __forceinline__ Tp ntload(const Tp* p) { return __builtin_nontemporal_load(p); }

// ws layout (floats):
//   ws[0      .. 4095] : per-block ce partials
//   ws[4096   .. 8191] : per-block smooth-L1 partials
//   ws[8192]           : agent loss

__device__ __forceinline__ float row_ce(float l0, float l1, float l2,
                                        float l3, float l4, float l5, int a)
{
    float m  = fmaxf(fmaxf(fmaxf(l0, l1), fmaxf(l2, l3)), fmaxf(l4, l5));
    float se = __expf(l0 - m) + __expf(l1 - m) + __expf(l2 - m) +
               __expf(l3 - m) + __expf(l4 - m) + __expf(l5 - m);
    float tgt = (a == 0) ? l0 : (a == 1) ? l1 : (a == 2) ? l2 :
                (a == 3) ? l3 : (a == 4) ? l4 : l5;
    return (m + __logf(se)) - tgt;
}

__device__ __forceinline__ float sl1(float v0, float v1, float rw)
{
    float d  = v0 - (rw + GAMMA * v1);
    float ad = fabsf(d);
    return (ad < 1.f) ? 0.5f * d * d : ad - 0.5f;
}

__global__ __launch_bounds__(BLK)
void fused_kernel(const float* __restrict__ arew,
                  const float* __restrict__ alp,
                  const float* __restrict__ aval,
                  const float* __restrict__ aent,
                  const float* __restrict__ olp,
                  const int*   __restrict__ oact,
                  const float* __restrict__ oval,
                  const float* __restrict__ orew,
                  float* __restrict__ ws)
{
    const int tid = threadIdx.x;
    __shared__ float s1[BLK], s2[BLK];

    if (blockIdx.x == 0) {
        // ----------------- agent loss: blocked reverse linear scan -----------------
        const int base = tid * CHUNK;

        float cR = 0.f, cG = 0.f;
        float nextv = aval[base + CHUNK];
        #pragma unroll 4
        for (int k4 = CHUNK - 4; k4 >= 0; k4 -= 4) {
            float4 r4 = *reinterpret_cast<const float4*>(&arew[base + k4]);
            float4 v4 = *reinterpret_cast<const float4*>(&aval[base + k4]);
            cR = GAMMA * cR + r4.w;  cG = GLAM * cG + (r4.w + GAMMA * nextv - v4.w);
            cR = GAMMA * cR + r4.z;  cG = GLAM * cG + (r4.z + GAMMA * v4.w  - v4.z);
            cR = GAMMA * cR + r4.y;  cG = GLAM * cG + (r4.y + GAMMA * v4.z  - v4.y);
            cR = GAMMA * cR + r4.x;  cG = GLAM * cG + (r4.x + GAMMA * v4.y  - v4.x);
            nextv = v4.x;
        }
        s1[tid] = cR; s2[tid] = cG;
        __syncthreads();

        if (tid == 0) {
            double aRd = 1.0, aGd = 1.0;
            for (int i = 0; i < CHUNK; ++i) { aRd *= 0.99; aGd *= 0.99 * 0.95; }
            const float aR = (float)aRd, aG = (float)aGd;
            float Rin = aval[T];
            float Gin = 0.f;
            for (int i = BLK - 1; i >= 0; --i) {
                float cr = s1[i], cg = s2[i];
                s1[i] = Rin; s2[i] = Gin;
                Rin = aR * Rin + cr;
                Gin = aG * Gin + cg;
            }
        }
        __syncthreads();
        float R = s1[tid], g = s2[tid];
        __syncthreads();

        float pl = 0.f, vl = 0.f;
        nextv = aval[base + CHUNK];
        #pragma unroll 4
        for (int k4 = CHUNK - 4; k4 >= 0; k4 -= 4) {
            float4 r4 = *reinterpret_cast<const float4*>(&arew[base + k4]);
            float4 v4 = *reinterpret_cast<const float4*>(&aval[base + k4]);
            float4 l4 = *reinterpret_cast<const float4*>(&alp [base + k4]);
            float4 e4 = *reinterpret_cast<const float4*>(&aent[base + k4]);

            R = GAMMA * R + r4.w; { float adv = R - v4.w; vl += 0.5f * adv * adv; }
            g = GLAM * g + (r4.w + GAMMA * nextv - v4.w); pl += -l4.w * g - ENT_C * e4.w;
            R = GAMMA * R + r4.z; { float adv = R - v4.z; vl += 0.5f * adv * adv; }
            g = GLAM * g + (r4.z + GAMMA * v4.w  - v4.z); pl += -l4.z * g - ENT_C * e4.z;
            R = GAMMA * R + r4.y; { float adv = R - v4.y; vl += 0.5f * adv * adv; }
            g = GLAM * g + (r4.y + GAMMA * v4.z  - v4.y); pl += -l4.y * g - ENT_C * e4.y;
            R = GAMMA * R + r4.x; { float adv = R - v4.x; vl += 0.5f * adv * adv; }
            g = GLAM * g + (r4.x + GAMMA * v4.y  - v4.x); pl += -l4.x * g - ENT_C * e4.x;
            nextv = v4.x;
        }
        s1[tid] = pl; s2[tid] = vl;
        __syncthreads();
        for (int stp = BLK / 2; stp > 0; stp >>= 1) {
            if (tid < stp) { s1[tid] += s1[tid + stp]; s2[tid] += s2[tid + stp]; }
            __syncthreads();
        }
        if (tid == 0) ws[2 * OPP_BLOCKS] = s1[0] + 0.5f * s2[0];
        return;
    }

    // -------- opponent loss: barrier-free, all loads issued up front --------
    const int bid  = blockIdx.x - 1;
    const int o    = bid >> 9;          // / BPO
    const int seg  = bid & (BPO - 1);
    const int row0 = seg * ROWS_PER_B;
    const size_t obase = (size_t)o * S;
    const size_t rbase = (size_t)o * (S - 1);

    const int r1 = row0 + 4 * tid;                 // quad 1: rows r1..r1+3
    const int r2 = row0 + (ROWS_PER_B / 2) + 4 * tid;  // quad 2

    // ---- issue ALL loads (~26 vmem, ~380 B/thread in flight) ----
    const f4* Lp1 = reinterpret_cast<const f4*>(olp + (obase + r1) * 6);
    const f4* Lp2 = reinterpret_cast<const f4*>(olp + (obase + r2) * 6);
    f4 a0 = ntload(Lp1 + 0), a1 = ntload(Lp1 + 1), a2 = ntload(Lp1 + 2);
    f4 a3 = ntload(Lp1 + 3), a4 = ntload(Lp1 + 4), a5 = ntload(Lp1 + 5);
    f4 b0 = ntload(Lp2 + 0), b1 = ntload(Lp2 + 1), b2 = ntload(Lp2 + 2);
    f4 b3 = ntload(Lp2 + 3), b4 = ntload(Lp2 + 4), b5 = ntload(Lp2 + 5);

    i4 A1 = ntload(reinterpret_cast<const i4*>(oact + obase + r1));
    i4 A2 = ntload(reinterpret_cast<const i4*>(oact + obase + r2));
    f4 V1 = ntload(reinterpret_cast<const f4*>(oval + obase + r1));
    f4 V2 = ntload(reinterpret_cast<const f4*>(oval + obase + r2));
    float V1e = oval[obase + r1 + 4];                              // always in-bounds (r1+4 < S)
    float V2e = (r2 + 4 <= S - 1) ? oval[obase + r2 + 4] : 0.f;    // guard last row only
    float w10 = ntload(orew + rbase + r1);
    float w11 = ntload(orew + rbase + r1 + 1);
    float w12 = ntload(orew + rbase + r1 + 2);
    float w13 = ntload(orew + rbase + r1 + 3);
    float w20 = ntload(orew + rbase + r2);
    float w21 = ntload(orew + rbase + r2 + 1);
    float w22 = ntload(orew + rbase + r2 + 2);
    float w23 = (r2 + 3 < S - 1) ? orew[rbase + r2 + 3] : 0.f;

    // ---- compute ----
    float ce_acc = 0.f, sl_acc = 0.f;

    ce_acc += row_ce(a0[0], a0[1], a0[2], a0[3], a1[0], a1[1], A1[0]);
    ce_acc += row_ce(a1[2], a1[3], a2[0], a2[1], a2[2], a2[3], A1[1]);
    ce_acc += row_ce(a3[0], a3[1], a3[2], a3[3], a4[0], a4[1], A1[2]);
    ce_acc += row_ce(a4[2], a4[3], a5[0], a5[1], a5[2], a5[3], A1[3]);
    ce_acc += row_ce(b0[0], b0[1], b0[2], b0[3], b1[0], b1[1], A2[0]);
    ce_acc += row_ce(b1[2], b1[3], b2[0], b2[1], b2[2], b2[3], A2[1]);
    ce_acc += row_ce(b3[0], b3[1], b3[2], b3[3], b4[0], b4[1], A2[2]);
    ce_acc += row_ce(b4[2], b4[3], b5[0], b5[1], b5[2], b5[3], A2[3]);

    sl_acc += sl1(V1[0], V1[1], w10);
    sl_acc += sl1(V1[1], V1[2], w11);
    sl_acc += sl1(V1[2], V1[3], w12);
    sl_acc += sl1(V1[3], V1e,   w13);
    sl_acc += sl1(V2[0], V2[1], w20);
    sl_acc += sl1(V2[1], V2[2], w21);
    sl_acc += sl1(V2[2], V2[3], w22);
    if (r2 + 3 < S - 1) sl_acc += sl1(V2[3], V2e, w23);

    // ---- block reduction ----
    s1[tid] = ce_acc; s2[tid] = sl_acc;
    __syncthreads();
    for (int stp = BLK / 2; stp > 0; stp >>= 1) {
        if (tid < stp) { s1[tid] += s1[tid + stp]; s2[tid] += s2[tid + stp]; }
        __syncthreads();
    }
    if (tid == 0) {
        ws[bid]              = s1[0];
        ws[OPP_BLOCKS + bid] = s2[0];
    }
}

__global__ __launch_bounds__(BLK)
void finalize_kernel(const float* __restrict__ ws,
                     const float* __restrict__ coefs,
                     float* __restrict__ out)
{
    const int tid = threadIdx.x;
    __shared__ float r1[BLK], r2[BLK];
    float tot = 0.f;
    for (int o = 0; o < O; ++o) {
        const float* cw = ws + o * BPO;
        const float* sw = ws + OPP_BLOCKS + o * BPO;
        r1[tid] = cw[tid] + cw[tid + BLK];
        r2[tid] = sw[tid] + sw[tid + BLK];
        __syncthreads();
        for (int stp = BLK / 2; stp > 0; stp >>= 1) {
            if (tid < stp) { r1[tid] += r1[tid + stp]; r2[tid] += r2[tid + stp]; }
            __syncthreads();
        }
        if (tid == 0)
            tot += coefs[o] * (r1[0] / (float)S + r2[0] / (float)(S - 1));
        __syncthreads();
    }
    if (tid == 0) out[0] = tot + ws[2 * OPP_BLOCKS];
}

extern "C" void kernel_launch(void* const* d_in, const int* in_sizes, int n_in,
                              void* d_out, int out_size, void* d_ws, size_t ws_size,
                              hipStream_t stream)
{
    const float* arew  = (const float*)d_in[0];
    const float* alp   = (const float*)d_in[1];
    const float* aval  = (const float*)d_in[2];
    const float* aent  = (const float*)d_in[3];
    const float* olp   = (const float*)d_in[4];
    const int*   oact  = (const int*)  d_in[5];
    const float* oval  = (const float*)d_in[6];
    const float* orew  = (const float*)d_in[7];
    const float* ocoef = (const float*)d_in[8];
    float* ws = (float*)d_ws;

    fused_kernel<<<1 + OPP_BLOCKS, BLK, 0, stream>>>(arew, alp, aval, aent,
                                                     olp, oact, oval, orew, ws);
    finalize_kernel<<<1, BLK, 0, stream>>>(ws, ocoef, (float*)d_out);
}